// Round 5
// baseline (1976.017 us; speedup 1.0000x reference)
//
#include <hip/hip_runtime.h>
#include <cstdint>
#include <cstddef>

typedef short s16x8 __attribute__((ext_vector_type(8)));
typedef float f32x4 __attribute__((ext_vector_type(4)));
typedef unsigned long long u64;

__device__ __forceinline__ f32x4 mfma16(s16x8 a, s16x8 b, f32x4 c) {
  return __builtin_amdgcn_mfma_f32_16x16x32_bf16(a, b, c, 0, 0, 0);
}

__device__ __forceinline__ unsigned short f2bf(float f) {
  unsigned u = __float_as_uint(f);
  u = (u + 0x7FFFu + ((u >> 16) & 1u)) >> 16;
  return (unsigned short)u;
}

// LLC-coherent ops (bypass L1/L2, hit the coherence point directly).
__device__ __forceinline__ u64 ld_llc64(const u64* q) {
  return __hip_atomic_load(q, __ATOMIC_RELAXED, __HIP_MEMORY_SCOPE_AGENT);
}
__device__ __forceinline__ float4 load16f_llc(const float* p) {
  union { u64 u[2]; float4 v; } r;
  const u64* q = (const u64*)p;
  r.u[0] = __hip_atomic_load(q,     __ATOMIC_RELAXED, __HIP_MEMORY_SCOPE_AGENT);
  r.u[1] = __hip_atomic_load(q + 1, __ATOMIC_RELAXED, __HIP_MEMORY_SCOPE_AGENT);
  return r.v;
}
__device__ __forceinline__ void store16f_llc(float* p, float4 v) {
  union { float4 v; u64 u[2]; } r; r.v = v;
  u64* q = (u64*)p;
  __hip_atomic_store(q,     r.u[0], __ATOMIC_RELAXED, __HIP_MEMORY_SCOPE_AGENT);
  __hip_atomic_store(q + 1, r.u[1], __ATOMIC_RELAXED, __HIP_MEMORY_SCOPE_AGENT);
}

// Depth-3 pipelined spin with sleep: ~3 loads in flight -> sampling interval
// ~RT/3; sleep keeps idle-poll pressure off the LLC. Monotonic >= check.
__device__ __forceinline__ void spin_tag(const int* t, int target) {
  if (target <= 0) return;
  int a = __hip_atomic_load(t, __ATOMIC_RELAXED, __HIP_MEMORY_SCOPE_AGENT);
  if (a >= target) return;
  int b = __hip_atomic_load(t, __ATOMIC_RELAXED, __HIP_MEMORY_SCOPE_AGENT);
  int c = __hip_atomic_load(t, __ATOMIC_RELAXED, __HIP_MEMORY_SCOPE_AGENT);
  while (a < target) {
    a = b; b = c;
    __builtin_amdgcn_s_sleep(1);
    c = __hip_atomic_load(t, __ATOMIC_RELAXED, __HIP_MEMORY_SCOPE_AGENT);
  }
}

// ---------------- fp32 -> bf16 conversion ----------------
__global__ void f2bf_kernel(const float* __restrict__ src,
                            unsigned short* __restrict__ dst, int n) {
  int i = (blockIdx.x * blockDim.x + threadIdx.x) * 4;
  if (i >= n) return;
  float4 v = *(const float4*)(src + i);
  ushort4 o;
  o.x = f2bf(v.x); o.y = f2bf(v.y); o.z = f2bf(v.z); o.w = f2bf(v.w);
  *(ushort4*)(dst + i) = o;
}

// ---------------- GEMM: C[M,N] = A[M,K] * W[N,K]^T + bias ----------------
__global__ __launch_bounds__(256) void gemm_bias(
    const unsigned short* __restrict__ A,
    const unsigned short* __restrict__ W,
    const float* __restrict__ bias,
    float* __restrict__ C,
    int M, int N, int K)
{
  __shared__ unsigned short As[128 * 40];
  __shared__ unsigned short Bs[128 * 40];
  const int bm = blockIdx.x, bn = blockIdx.y;
  const int tid = threadIdx.x;
  const int lane = tid & 63, wave = tid >> 6;
  const int wm = wave & 1, wn = wave >> 1;
  const int lr = lane & 15, quad = lane >> 4;
  f32x4 acc[4][4] = {};
  const size_t abase = (size_t)bm * 128 * K;
  const size_t bbase = (size_t)bn * 128 * K;
  for (int k0 = 0; k0 < K; k0 += 32) {
#pragma unroll
    for (int u0 = 0; u0 < 2; u0++) {
      int u = tid + u0 * 256;
      int row = u >> 2, seg = u & 3;
      *(uint4*)(As + row * 40 + seg * 8) =
          *(const uint4*)(A + abase + (size_t)row * K + k0 + seg * 8);
      *(uint4*)(Bs + row * 40 + seg * 8) =
          *(const uint4*)(W + bbase + (size_t)row * K + k0 + seg * 8);
    }
    __syncthreads();
    s16x8 af[4], bf[4];
#pragma unroll
    for (int i = 0; i < 4; i++)
      af[i] = *(const s16x8*)(As + (wm * 64 + i * 16 + lr) * 40 + quad * 8);
#pragma unroll
    for (int j = 0; j < 4; j++)
      bf[j] = *(const s16x8*)(Bs + (wn * 64 + j * 16 + lr) * 40 + quad * 8);
#pragma unroll
    for (int i = 0; i < 4; i++)
#pragma unroll
      for (int j = 0; j < 4; j++)
        acc[i][j] = mfma16(af[i], bf[j], acc[i][j]);
    __syncthreads();
  }
#pragma unroll
  for (int i = 0; i < 4; i++)
#pragma unroll
    for (int j = 0; j < 4; j++) {
      int col = bn * 128 + wn * 64 + j * 16 + lr;
      float bv = bias ? bias[col] : 0.0f;
#pragma unroll
      for (int r = 0; r < 4; r++) {
        int row = bm * 128 + wm * 64 + i * 16 + quad * 4 + r;
        C[(size_t)row * N + col] = acc[i][j][r] + bv;
      }
    }
}

// ---------------- dataflow 3-stage pipelined LSTM ----------------
// R11 = R10 minus the producer store-drain (the one removable LLC RT on the
// period-critical self-loops):
//   * h1/h2 words are 32-bit stamped atomics: (stamp<<16)|bf16, stamp =
//     producer_step+1 (zero-init == h(-1)=0). One u32 store per thread.
//   * The per-block tag becomes a HINT for data readiness: tid0 stores it
//     after a plain __syncthreads (all h stores ISSUED) with NO vmcnt(0).
//     Consumers poll the same 8 tag lines as before (no R7-style data-poll
//     flood), then load the stamped words and verify stamps IN-REGISTER,
//     retrying only within the tag-overtakes-data window (~store skew).
//   * The tag keeps its read-certification role for the anti-trample guards:
//     all h/P reads complete before syncA < syncC < tag store, so tag >= X
//     still implies "block finished reading step X's inputs". Guard algebra
//     unchanged from R10.
//   * cls1 (P producer) keeps vmcnt(0): P is plain fp32, unstampable; cls1's
//     latency is pipeline phase offset, not period-critical.
// Kept from R10: single parallel poll (data lanes 0-7, guard lanes 8-15/8),
// cls2 P-prefetch, no syncB (pre[] exchange is wave-internal), ring-4 slots,
// R6 single-tid0 publish discipline.
// Classes (64 blocks each, 16 output dims per block, weights in VGPRs):
//   cls0 L1 : h1(s) = gate(ih(s) + Whh0 h1(s-1))   tagL1
//   cls1 L2b: P(s)  = Wih1 h1(s) + b1  -> 4-ring   tagL2b (point-to-point)
//   cls2 L2a: h2(s) = gate(P(s) + Whh1 h2(s-1))    tagL2a; writes out
// Anti-trample (ring-4, all lagging): cls0 h1(s) over h1(s-4) needs peers
// tagL1>=s and cls1 tagL2b>=s-3; cls1 P(s) over P(s-4) needs partner
// tagL2a>=s-3; cls2 h2(s) over h2(s-4) needs peers tagL2a>=s. A consumer
// mid-read at step u has not yet published u, so its slot cannot be
// overwritten under it -> stamp check can only see {stale, wanted}, never
// future; stale -> bounded retry (data in flight). Deadlock-free.
#define TSTRIDE 32          // ints per tag (128B line)
#define HSLOT  32768        // u32 words per h slot: 64 blk * 32 batch * 16 dim
#define PSLOT  (64 * 2048)  // floats per P slot: 64 blk * 32 batch * 64 col

__global__ __launch_bounds__(512, 2) void lstm_pipe(
    const float* __restrict__ ih,             // [(b*T+t)*4096 + g*1024 + d]
    const unsigned short* __restrict__ Whh0,  // [4096,1024] bf16
    const unsigned short* __restrict__ Wih1,  // [4096,1024] bf16
    const unsigned short* __restrict__ Whh1,  // [4096,1024] bf16
    const float* __restrict__ b1,             // [4096] fp32
    unsigned* __restrict__ h1x,               // [4][64][32][16] u32 (zeroed)
    unsigned* __restrict__ h2x,               // [4][64][32][16] u32 (zeroed)
    float* __restrict__ Pring,                // [4][64][32][64] fp32
    int* __restrict__ tags,                   // [3][64][TSTRIDE] (zeroed)
    float* __restrict__ out)                  // [32][256][1024] fp32
{
  const int T = 256, H = 1024;
  const int cls = blockIdx.x >> 6;
  const int blk = blockIdx.x & 63;
  const int tid = threadIdx.x;
  const int lane = tid & 63, wv = tid >> 6;
  const int lr = lane & 15, quad = lane >> 4;

  __shared__ float red[8][32][68];
  __shared__ float pre[32][68];

  const unsigned short* W = (cls == 0) ? Whh0 : (cls == 1) ? Wih1 : Whh1;
  s16x8 bfrag[4][4];
#pragma unroll
  for (int g = 0; g < 4; g++) {
    const unsigned short* wp =
        W + (size_t)(g * 1024 + blk * 16 + lr) * 1024 + wv * 128 + quad * 8;
#pragma unroll
    for (int kb = 0; kb < 4; kb++) bfrag[g][kb] = *(const s16x8*)(wp + kb * 32);
  }

  int* tagL1  = tags;
  int* tagL2b = tags + 64 * TSTRIDE;
  int* tagL2a = tags + 128 * TSTRIDE;
  int* mytag  = tags + (cls * 64 + blk) * TSTRIDE;

  // ---- per-lane poll assignment: one parallel spin covers everything ----
  const int* pollPtr = nullptr;
  int pollDelta = 0;
  if (cls == 0) {
    if (lane < 8)       { pollPtr = tagL1  + (8 * wv + lane) * TSTRIDE;     pollDelta = 0;  }
    else if (lane < 16) { pollPtr = tagL2b + (8 * wv + lane - 8) * TSTRIDE; pollDelta = -3; }
  } else if (cls == 1) {
    if (lane < 8)       { pollPtr = tagL1  + (8 * wv + lane) * TSTRIDE;     pollDelta = 1;  }
    else if (lane == 8) { pollPtr = tagL2a + blk * TSTRIDE;                 pollDelta = -3; }
  } else {
    if (lane < 8)       { pollPtr = tagL2a + (8 * wv + lane) * TSTRIDE;     pollDelta = 0;  }
    else if (lane == 8) { pollPtr = tagL2b + blk * TSTRIDE;                 pollDelta = 1;  }
  }

  const int batch = tid >> 4, jj = tid & 15;
  float cst = 0.0f;

  const int o = tid * 4;
  const int b2 = o >> 6, col0 = o & 63;
  const int gg_ = col0 >> 4, j0 = col0 & 15;
  const float* ihp0 = ih + (size_t)b2 * T * 4096 + gg_ * 1024 + blk * 16 + j0;

  float4 iv = {0.f, 0.f, 0.f, 0.f};
  if (cls == 0)      iv = *(const float4*)(ihp0);
  else if (cls == 1) iv = *(const float4*)(b1 + gg_ * 1024 + blk * 16 + j0);

  for (int s = 0; s < T; s++) {
    // ---- single parallel poll: data HINTS + anti-trample guards ----
    if (pollPtr) spin_tag(pollPtr, s + pollDelta);
    asm volatile("" ::: "memory");  // no hoisting data loads above polls

    // cls2: issue partner-P load NOW so its RT hides under MFMA
    float4 smp = {0.f, 0.f, 0.f, 0.f};
    if (cls == 2)
      smp = load16f_llc(Pring + (size_t)(s & 3) * PSLOT + blk * 2048 + b2 * 64 + col0);

    // source: cls0 h1(s-1) want stamp s; cls1 h1(s) want s+1;
    // cls2 h2(s-1) want s. slot = producer_step & 3.
    const unsigned* src =
        (cls == 0) ? h1x + ((s + 3) & 3) * HSLOT
      : (cls == 1) ? h1x + (s & 3) * HSLOT
                   : h2x + ((s + 3) & 3) * HSLOT;
    const unsigned stamp = (cls == 1) ? (unsigned)(s + 1) : (unsigned)s;
    const u64 want = ((u64)stamp << 16) | ((u64)stamp << 48);
    const u64 MSK = 0xFFFF0000FFFF0000ull;

    // hoist all 32 stamped u64 loads (one LLC flight for the whole step)
    u64 w[32];
#pragma unroll
    for (int kb = 0; kb < 4; kb++) {
      const int d = wv * 128 + kb * 32 + quad * 8;       // global k-dim
      const unsigned* pp = src + (d >> 4) * 512 + (d & 15);
      const u64* q0 = (const u64*)(pp + lr * 16);
      const u64* q1 = (const u64*)(pp + (16 + lr) * 16);
#pragma unroll
      for (int i = 0; i < 4; i++) {
        w[kb * 8 + i]     = ld_llc64(q0 + i);
        w[kb * 8 + 4 + i] = ld_llc64(q1 + i);
      }
    }
    // stamp verify; retry only in the tag-overtook-data window (rare)
    u64 bad = 0;
#pragma unroll
    for (int i = 0; i < 32; i++) bad |= (w[i] ^ want) & MSK;
    while (bad) {
      __builtin_amdgcn_s_sleep(2);
      bad = 0;
#pragma unroll
      for (int kb = 0; kb < 4; kb++) {
        const int d = wv * 128 + kb * 32 + quad * 8;
        const unsigned* pp = src + (d >> 4) * 512 + (d & 15);
        const u64* q0 = (const u64*)(pp + lr * 16);
        const u64* q1 = (const u64*)(pp + (16 + lr) * 16);
#pragma unroll
        for (int i = 0; i < 4; i++) {
          w[kb * 8 + i]     = ld_llc64(q0 + i);
          w[kb * 8 + 4 + i] = ld_llc64(q1 + i);
        }
      }
#pragma unroll
      for (int i = 0; i < 32; i++) bad |= (w[i] ^ want) & MSK;
    }

    f32x4 acc0[4] = {}, acc1[4] = {};
#pragma unroll
    for (int kb = 0; kb < 4; kb++) {
      union { unsigned u[4]; s16x8 v; } A0, A1;
#pragma unroll
      for (int i = 0; i < 4; i++) {
        u64 r = w[kb * 8 + i];
        A0.u[i] = __builtin_amdgcn_perm((unsigned)(r >> 32), (unsigned)r, 0x05040100u);
        r = w[kb * 8 + 4 + i];
        A1.u[i] = __builtin_amdgcn_perm((unsigned)(r >> 32), (unsigned)r, 0x05040100u);
      }
#pragma unroll
      for (int g = 0; g < 4; g++) {
        acc0[g] = mfma16(A0.v, bfrag[g][kb], acc0[g]);
        acc1[g] = mfma16(A1.v, bfrag[g][kb], acc1[g]);
      }
    }
#pragma unroll
    for (int g = 0; g < 4; g++)
#pragma unroll
      for (int r = 0; r < 4; r++) {
        red[wv][quad * 4 + r][g * 16 + lr] = acc0[g][r];
        red[wv][16 + quad * 4 + r][g * 16 + lr] = acc1[g][r];
      }
    __syncthreads();  // A (orders: guards < h-stores; red writes < reads)

    // ---- reduce 8 partials + iv (cls2: iv = partner's P(s), prefetched) ----
    float4 sm = (cls == 2) ? smp : iv;
#pragma unroll
    for (int p = 0; p < 8; p++) {
      float4 r = *(const float4*)&red[p][b2][col0];
      sm.x += r.x; sm.y += r.y; sm.z += r.z; sm.w += r.w;
    }

    if (cls == 0 && s + 1 < T)
      iv = *(const float4*)(ihp0 + (size_t)(s + 1) * 4096);

    float hv = 0.0f;
    if (cls == 1) {
      // P(s) = pre-activations, straight to the ring (no gates)
      store16f_llc(Pring + (size_t)(s & 3) * PSLOT + blk * 2048 + b2 * 64 + col0, sm);
    } else {
      // gate exchange is WAVE-INTERNAL: writer lanes of row b2 == reader
      // lanes of batch==b2 (same 16 threads); lgkmcnt orders it.
      *(float4*)&pre[b2][col0] = sm;
      float pi = pre[batch][jj];
      float pf = pre[batch][16 + jj];
      float pg = pre[batch][32 + jj];
      float po = pre[batch][48 + jj];
      float ig = 1.0f / (1.0f + __expf(-pi));
      float fg = 1.0f / (1.0f + __expf(-pf));
      float g  = 1.0f - 2.0f / (__expf(2.0f * pg) + 1.0f);  // tanh, safe
      float og = 1.0f / (1.0f + __expf(-po));
      cst = fg * cst + ig * g;
      hv = og * (1.0f - 2.0f / (__expf(2.0f * cst) + 1.0f));
      // stamped publish: fire-and-forget, NO drain. Stamp = s+1.
      unsigned word = ((unsigned)(s + 1) << 16) | (unsigned)f2bf(hv);
      unsigned* dst = (cls == 0 ? h1x : h2x) + (s & 3) * HSLOT;
      __hip_atomic_store(dst + blk * 512 + batch * 16 + jj, word,
                         __ATOMIC_RELAXED, __HIP_MEMORY_SCOPE_AGENT);
    }
    // cls1 certifies P visibility (no stamps on fp32) -> drain. cls0/cls2:
    // barrier only (all h stores ISSUED); stamps cover in-flight stores.
    if (cls == 1) asm volatile("s_waitcnt vmcnt(0)" ::: "memory");
    __syncthreads();  // C (red WAR + all-waves-issued before tag)
    if (tid == 0)
      __hip_atomic_store(mytag, s + 1, __ATOMIC_RELAXED, __HIP_MEMORY_SCOPE_AGENT);
    if (cls == 2)  // out store after publish: not on the forward path
      out[((size_t)(batch * T + s)) * H + blk * 16 + jj] = hv;
  }
}

// ---------------- launcher ----------------
extern "C" void kernel_launch(void* const* d_in, const int* in_sizes, int n_in,
                              void* d_out, int out_size, void* d_ws, size_t ws_size,
                              hipStream_t stream) {
  const float* x    = (const float*)d_in[0];
  const float* Wih0 = (const float*)d_in[1];
  const float* Whh0 = (const float*)d_in[2];
  const float* b0   = (const float*)d_in[3];
  const float* Wih1 = (const float*)d_in[4];
  const float* Whh1 = (const float*)d_in[5];
  const float* b1   = (const float*)d_in[6];
  float* out = (float*)d_out;

  const size_t NW = 4096ull * 1024;  // weight elems
  const size_t NX = 8192ull * 1024;  // x elems (B*T x H)

  char* ws = (char*)d_ws;
  size_t off = 0;
  auto alloc = [&](size_t bytes) {
    char* p = ws + off;
    off += (bytes + 255) & ~(size_t)255;
    return p;
  };
  unsigned short* wih0b = (unsigned short*)alloc(NW * 2);
  unsigned short* whh0b = (unsigned short*)alloc(NW * 2);
  unsigned short* wih1b = (unsigned short*)alloc(NW * 2);
  unsigned short* whh1b = (unsigned short*)alloc(NW * 2);
  unsigned short* xb    = (unsigned short*)alloc(NX * 2);
  float* ihbuf          = (float*)alloc(8192ull * 4096 * 4);
  unsigned* h1x         = (unsigned*)alloc(4ull * HSLOT * 4);
  unsigned* h2x         = (unsigned*)alloc(4ull * HSLOT * 4);
  float* Pring          = (float*)alloc(4ull * PSLOT * 4);
  int* tags             = (int*)alloc(3ull * 64 * TSTRIDE * 4);

  hipMemsetAsync(tags, 0, 3ull * 64 * TSTRIDE * 4, stream);
  hipMemsetAsync(h1x, 0, 4ull * HSLOT * 4, stream);
  hipMemsetAsync(h2x, 0, 4ull * HSLOT * 4, stream);

  f2bf_kernel<<<NW / 1024, 256, 0, stream>>>(Wih0, wih0b, (int)NW);
  f2bf_kernel<<<NW / 1024, 256, 0, stream>>>(Whh0, whh0b, (int)NW);
  f2bf_kernel<<<NW / 1024, 256, 0, stream>>>(Wih1, wih1b, (int)NW);
  f2bf_kernel<<<NW / 1024, 256, 0, stream>>>(Whh1, whh1b, (int)NW);
  f2bf_kernel<<<NX / 1024, 256, 0, stream>>>(x, xb, (int)NX);

  // layer-1 input projection (one big GEMM), then the dataflow pipeline
  gemm_bias<<<dim3(64, 32), 256, 0, stream>>>(xb, wih0b, b0, ihbuf, 8192, 4096, 1024);
  lstm_pipe<<<192, 512, 0, stream>>>(ihbuf, whh0b, wih1b, whh1b, b1,
                                     h1x, h2x, Pring, tags, out);
}

// Round 6
// 1332.231 us; speedup vs baseline: 1.4832x; 1.4832x over previous
//
#include <hip/hip_runtime.h>
#include <cstdint>
#include <cstddef>

typedef short s16x8 __attribute__((ext_vector_type(8)));
typedef float f32x4 __attribute__((ext_vector_type(4)));
typedef unsigned long long u64;

__device__ __forceinline__ f32x4 mfma16(s16x8 a, s16x8 b, f32x4 c) {
  return __builtin_amdgcn_mfma_f32_16x16x32_bf16(a, b, c, 0, 0, 0);
}

__device__ __forceinline__ unsigned short f2bf(float f) {
  unsigned u = __float_as_uint(f);
  u = (u + 0x7FFFu + ((u >> 16) & 1u)) >> 16;
  return (unsigned short)u;
}

// LLC-coherent ops (bypass L1/L2, hit the coherence point directly).
__device__ __forceinline__ u64 ld_llc64(const u64* q) {
  return __hip_atomic_load(q, __ATOMIC_RELAXED, __HIP_MEMORY_SCOPE_AGENT);
}
__device__ __forceinline__ float4 load16f_llc(const float* p) {
  union { u64 u[2]; float4 v; } r;
  const u64* q = (const u64*)p;
  r.u[0] = __hip_atomic_load(q,     __ATOMIC_RELAXED, __HIP_MEMORY_SCOPE_AGENT);
  r.u[1] = __hip_atomic_load(q + 1, __ATOMIC_RELAXED, __HIP_MEMORY_SCOPE_AGENT);
  return r.v;
}
__device__ __forceinline__ void store16f_llc(float* p, float4 v) {
  union { float4 v; u64 u[2]; } r; r.v = v;
  u64* q = (u64*)p;
  __hip_atomic_store(q,     r.u[0], __ATOMIC_RELAXED, __HIP_MEMORY_SCOPE_AGENT);
  __hip_atomic_store(q + 1, r.u[1], __ATOMIC_RELAXED, __HIP_MEMORY_SCOPE_AGENT);
}

// Depth-3 pipelined spin with sleep: ~3 loads in flight -> sampling interval
// ~RT/3; sleep keeps idle-poll pressure off the LLC. Monotonic >= check.
__device__ __forceinline__ void spin_tag(const int* t, int target) {
  if (target <= 0) return;
  int a = __hip_atomic_load(t, __ATOMIC_RELAXED, __HIP_MEMORY_SCOPE_AGENT);
  if (a >= target) return;
  int b = __hip_atomic_load(t, __ATOMIC_RELAXED, __HIP_MEMORY_SCOPE_AGENT);
  int c = __hip_atomic_load(t, __ATOMIC_RELAXED, __HIP_MEMORY_SCOPE_AGENT);
  while (a < target) {
    a = b; b = c;
    __builtin_amdgcn_s_sleep(1);
    c = __hip_atomic_load(t, __ATOMIC_RELAXED, __HIP_MEMORY_SCOPE_AGENT);
  }
}

// ---------------- fp32 -> bf16 conversion ----------------
__global__ void f2bf_kernel(const float* __restrict__ src,
                            unsigned short* __restrict__ dst, int n) {
  int i = (blockIdx.x * blockDim.x + threadIdx.x) * 4;
  if (i >= n) return;
  float4 v = *(const float4*)(src + i);
  ushort4 o;
  o.x = f2bf(v.x); o.y = f2bf(v.y); o.z = f2bf(v.z); o.w = f2bf(v.w);
  *(ushort4*)(dst + i) = o;
}

// ---------------- GEMM: C[M,N] = A[M,K] * W[N,K]^T + bias ----------------
__global__ __launch_bounds__(256) void gemm_bias(
    const unsigned short* __restrict__ A,
    const unsigned short* __restrict__ W,
    const float* __restrict__ bias,
    float* __restrict__ C,
    int M, int N, int K)
{
  __shared__ unsigned short As[128 * 40];
  __shared__ unsigned short Bs[128 * 40];
  const int bm = blockIdx.x, bn = blockIdx.y;
  const int tid = threadIdx.x;
  const int lane = tid & 63, wave = tid >> 6;
  const int wm = wave & 1, wn = wave >> 1;
  const int lr = lane & 15, quad = lane >> 4;
  f32x4 acc[4][4] = {};
  const size_t abase = (size_t)bm * 128 * K;
  const size_t bbase = (size_t)bn * 128 * K;
  for (int k0 = 0; k0 < K; k0 += 32) {
#pragma unroll
    for (int u0 = 0; u0 < 2; u0++) {
      int u = tid + u0 * 256;
      int row = u >> 2, seg = u & 3;
      *(uint4*)(As + row * 40 + seg * 8) =
          *(const uint4*)(A + abase + (size_t)row * K + k0 + seg * 8);
      *(uint4*)(Bs + row * 40 + seg * 8) =
          *(const uint4*)(W + bbase + (size_t)row * K + k0 + seg * 8);
    }
    __syncthreads();
    s16x8 af[4], bf[4];
#pragma unroll
    for (int i = 0; i < 4; i++)
      af[i] = *(const s16x8*)(As + (wm * 64 + i * 16 + lr) * 40 + quad * 8);
#pragma unroll
    for (int j = 0; j < 4; j++)
      bf[j] = *(const s16x8*)(Bs + (wn * 64 + j * 16 + lr) * 40 + quad * 8);
#pragma unroll
    for (int i = 0; i < 4; i++)
#pragma unroll
      for (int j = 0; j < 4; j++)
        acc[i][j] = mfma16(af[i], bf[j], acc[i][j]);
    __syncthreads();
  }
#pragma unroll
  for (int i = 0; i < 4; i++)
#pragma unroll
    for (int j = 0; j < 4; j++) {
      int col = bn * 128 + wn * 64 + j * 16 + lr;
      float bv = bias ? bias[col] : 0.0f;
#pragma unroll
      for (int r = 0; r < 4; r++) {
        int row = bm * 128 + wm * 64 + i * 16 + quad * 4 + r;
        C[(size_t)row * N + col] = acc[i][j][r] + bv;
      }
    }
}

// ---------------- dataflow 3-stage pipelined LSTM ----------------
// R12 = R10 (best verified: 1067us) + two tail cuts. R7/R11's stamp scheme is
// abandoned for good: relaxed-store visibility skew ~ 1 RT, so tag-hint
// always overtakes data -> retry storm (FETCH +132MB both times).
//   1. cls0's ih prefetch moves AFTER the drain: the tail vmcnt(0) no longer
//      waits on a cold HBM load (~900cy), only on the h-store ack. The
//      prefetch gets a full period to complete off the critical path.
//   2. syncC + tid0-publish replaced by double-buffered red[] (parity s&1)
//      + last-arriver publish: each wave drains its OWN stores (vmcnt(0)),
//      lane0 does an LDS atomicAdd on a monotonic counter; the 8th arrival
//      (old == 8(s+1)-1) stores the tag. Barriers/step: 2 -> 1 (syncA only).
//      Safety: red WAR across parities is ordered by syncA program-order
//      transitivity (a wave writing red[s&1] at step s passed syncA(s-1),
//      which requires all waves done with reduce(s-2) -- the only readers of
//      that parity). pre[] is wave-internal (writer rows 4wv..4wv+3 ==
//      reader rows). Tag semantics unchanged: publish certifies all waves'
//      stores DRAINED + reads retired => R10's anti-trample algebra intact.
//      LDS 78KB -> 148KB: 1 block/CU, but 192 blocks < 256 CUs (no change).
// Kept from R10: single parallel poll (data lanes 0-7, guard lanes 8-15/8),
// cls2 P-prefetch, no syncB, ring-4 h slots, depth-3+sleep spin.
// Classes (64 blocks each, 16 output dims per block, weights in VGPRs):
//   cls0 L1 : h1(s) = gate(ih(s) + Whh0 h1(s-1))   tagL1
//   cls1 L2b: P(s)  = Wih1 h1(s) + b1  -> 4-ring   tagL2b (point-to-point)
//   cls2 L2a: h2(s) = gate(P(s) + Whh1 h2(s-1))    tagL2a; writes out
// Anti-trample (ring-4, all lagging): cls0 h1(s) over h1(s-4) needs peers
// tagL1>=s and cls1 tagL2b>=s-3; cls1 P(s) over P(s-4) needs partner
// tagL2a>=s-3; cls2 h2(s) over h2(s-4) needs peers tagL2a>=s. Deadlock-free.
#define TSTRIDE 32          // ints per tag (128B line)
#define HSLOT  32768        // shorts per h slot: 64 blk * 32 batch * 16 dim
#define PSLOT  (64 * 2048)  // floats per P slot: 64 blk * 32 batch * 64 col

__global__ __launch_bounds__(512, 2) void lstm_pipe(
    const float* __restrict__ ih,             // [(b*T+t)*4096 + g*1024 + d]
    const unsigned short* __restrict__ Whh0,  // [4096,1024] bf16
    const unsigned short* __restrict__ Wih1,  // [4096,1024] bf16
    const unsigned short* __restrict__ Whh1,  // [4096,1024] bf16
    const float* __restrict__ b1,             // [4096] fp32
    unsigned short* __restrict__ h1x,         // [4][64][32][16] bf16 (zeroed)
    unsigned short* __restrict__ h2x,         // [4][64][32][16] bf16 (zeroed)
    float* __restrict__ Pring,                // [4][64][32][64] fp32
    int* __restrict__ tags,                   // [3][64][TSTRIDE] (zeroed)
    float* __restrict__ out)                  // [32][256][1024] fp32
{
  const int T = 256, H = 1024;
  const int cls = blockIdx.x >> 6;
  const int blk = blockIdx.x & 63;
  const int tid = threadIdx.x;
  const int lane = tid & 63, wv = tid >> 6;
  const int lr = lane & 15, quad = lane >> 4;

  __shared__ float red[2][8][32][68];   // double-buffered by step parity
  __shared__ float pre[32][68];
  __shared__ unsigned cnt;              // monotonic wave-arrival counter

  const unsigned short* W = (cls == 0) ? Whh0 : (cls == 1) ? Wih1 : Whh1;
  s16x8 bfrag[4][4];
#pragma unroll
  for (int g = 0; g < 4; g++) {
    const unsigned short* wp =
        W + (size_t)(g * 1024 + blk * 16 + lr) * 1024 + wv * 128 + quad * 8;
#pragma unroll
    for (int kb = 0; kb < 4; kb++) bfrag[g][kb] = *(const s16x8*)(wp + kb * 32);
  }

  int* tagL1  = tags;
  int* tagL2b = tags + 64 * TSTRIDE;
  int* tagL2a = tags + 128 * TSTRIDE;
  int* mytag  = tags + (cls * 64 + blk) * TSTRIDE;

  // ---- per-lane poll assignment: one parallel spin covers everything ----
  const int* pollPtr = nullptr;
  int pollDelta = 0;
  if (cls == 0) {
    if (lane < 8)       { pollPtr = tagL1  + (8 * wv + lane) * TSTRIDE;     pollDelta = 0;  }
    else if (lane < 16) { pollPtr = tagL2b + (8 * wv + lane - 8) * TSTRIDE; pollDelta = -3; }
  } else if (cls == 1) {
    if (lane < 8)       { pollPtr = tagL1  + (8 * wv + lane) * TSTRIDE;     pollDelta = 1;  }
    else if (lane == 8) { pollPtr = tagL2a + blk * TSTRIDE;                 pollDelta = -3; }
  } else {
    if (lane < 8)       { pollPtr = tagL2a + (8 * wv + lane) * TSTRIDE;     pollDelta = 0;  }
    else if (lane == 8) { pollPtr = tagL2b + blk * TSTRIDE;                 pollDelta = 1;  }
  }

  const int batch = tid >> 4, jj = tid & 15;
  float cst = 0.0f;

  const int o = tid * 4;
  const int b2 = o >> 6, col0 = o & 63;
  const int gg_ = col0 >> 4, j0 = col0 & 15;
  const float* ihp0 = ih + (size_t)b2 * T * 4096 + gg_ * 1024 + blk * 16 + j0;

  float4 iv = {0.f, 0.f, 0.f, 0.f};
  if (cls == 0)      iv = *(const float4*)(ihp0);
  else if (cls == 1) iv = *(const float4*)(b1 + gg_ * 1024 + blk * 16 + j0);

  if (tid == 0) cnt = 0;
  __syncthreads();

  for (int s = 0; s < T; s++) {
    // ---- single parallel poll: data tags + anti-trample guards ----
    if (pollPtr) spin_tag(pollPtr, s + pollDelta);
    asm volatile("" ::: "memory");  // no hoisting data loads above polls

    // cls2: issue partner-P load NOW so its RT hides under MFMA
    float4 smp = {0.f, 0.f, 0.f, 0.f};
    if (cls == 2)
      smp = load16f_llc(Pring + (size_t)(s & 3) * PSLOT + blk * 2048 + b2 * 64 + col0);

    // source: cls0 h1(s-1); cls1 h1(s); cls2 h2(s-1). slot = step & 3.
    const unsigned short* src =
        (cls == 0) ? h1x + ((s + 3) & 3) * HSLOT
      : (cls == 1) ? h1x + (s & 3) * HSLOT
                   : h2x + ((s + 3) & 3) * HSLOT;

    // hoist all fragment loads (one LLC latency for the whole step)
    u64 r0[4][2], r1[4][2];
#pragma unroll
    for (int kb = 0; kb < 4; kb++) {
      const int d = wv * 128 + kb * 32 + quad * 8;       // global k-dim
      const unsigned short* pp = src + (d >> 4) * 512 + (d & 15);
      const u64* q0 = (const u64*)(pp + lr * 16);
      const u64* q1 = (const u64*)(pp + (16 + lr) * 16);
      r0[kb][0] = ld_llc64(q0); r0[kb][1] = ld_llc64(q0 + 1);
      r1[kb][0] = ld_llc64(q1); r1[kb][1] = ld_llc64(q1 + 1);
    }

    f32x4 acc0[4] = {}, acc1[4] = {};
#pragma unroll
    for (int kb = 0; kb < 4; kb++) {
      union { u64 u[2]; s16x8 v; } A0, A1;
      A0.u[0] = r0[kb][0]; A0.u[1] = r0[kb][1];
      A1.u[0] = r1[kb][0]; A1.u[1] = r1[kb][1];
#pragma unroll
      for (int g = 0; g < 4; g++) {
        acc0[g] = mfma16(A0.v, bfrag[g][kb], acc0[g]);
        acc1[g] = mfma16(A1.v, bfrag[g][kb], acc1[g]);
      }
    }
    float (*redp)[32][68] = red[s & 1];
#pragma unroll
    for (int g = 0; g < 4; g++)
#pragma unroll
      for (int r = 0; r < 4; r++) {
        redp[wv][quad * 4 + r][g * 16 + lr] = acc0[g][r];
        redp[wv][16 + quad * 4 + r][g * 16 + lr] = acc1[g][r];
      }
    __syncthreads();  // A (the only barrier: guards < h-stores; red w < r)

    // ---- reduce 8 partials + iv (cls2: iv = partner's P(s), prefetched) ----
    float4 sm = (cls == 2) ? smp : iv;
#pragma unroll
    for (int p = 0; p < 8; p++) {
      float4 r = *(const float4*)&redp[p][b2][col0];
      sm.x += r.x; sm.y += r.y; sm.z += r.z; sm.w += r.w;
    }

    float hv = 0.0f;
    if (cls == 1) {
      // P(s) = pre-activations, straight to the ring (no gates)
      store16f_llc(Pring + (size_t)(s & 3) * PSLOT + blk * 2048 + b2 * 64 + col0, sm);
    } else {
      // gate exchange is WAVE-INTERNAL: writer lanes of row b2 == reader
      // lanes of batch==b2 (same 16 threads); lgkmcnt orders it.
      *(float4*)&pre[b2][col0] = sm;
      float pi = pre[batch][jj];
      float pf = pre[batch][16 + jj];
      float pg = pre[batch][32 + jj];
      float po = pre[batch][48 + jj];
      float ig = 1.0f / (1.0f + __expf(-pi));
      float fg = 1.0f / (1.0f + __expf(-pf));
      float g  = 1.0f - 2.0f / (__expf(2.0f * pg) + 1.0f);  // tanh, safe
      float og = 1.0f / (1.0f + __expf(-po));
      cst = fg * cst + ig * g;
      hv = og * (1.0f - 2.0f / (__expf(2.0f * cst) + 1.0f));
      unsigned hb32 = f2bf(hv);
      unsigned other = __shfl_xor(hb32, 1);  // partner (same batch, jj^1)
      unsigned* dst = (unsigned*)((cls == 0 ? h1x : h2x) + (s & 3) * HSLOT);
      if ((tid & 1) == 0)
        __hip_atomic_store(dst + blk * 256 + batch * 8 + (jj >> 1),
                           (hb32 & 0xFFFFu) | (other << 16),
                           __ATOMIC_RELAXED, __HIP_MEMORY_SCOPE_AGENT);
    }
    // per-wave drain of OWN stores, then last-arriver publishes the tag.
    // No block barrier in the tail; waves free-run into the next poll.
    asm volatile("s_waitcnt vmcnt(0)" ::: "memory");
    if (lane == 0) {
      unsigned old = atomicAdd(&cnt, 1u);
      if (old == 8u * (unsigned)(s + 1) - 1u)
        __hip_atomic_store(mytag, s + 1, __ATOMIC_RELAXED, __HIP_MEMORY_SCOPE_AGENT);
    }
    if (cls == 2)  // out store after publish: not on the forward path
      out[((size_t)(batch * T + s)) * H + blk * 16 + jj] = hv;
    // cls0: ih prefetch AFTER the drain -> HBM latency hides under the next
    // poll+load+MFMA phase instead of sitting inside the drain.
    if (cls == 0 && s + 1 < T)
      iv = *(const float4*)(ihp0 + (size_t)(s + 1) * 4096);
  }
}

// ---------------- launcher ----------------
extern "C" void kernel_launch(void* const* d_in, const int* in_sizes, int n_in,
                              void* d_out, int out_size, void* d_ws, size_t ws_size,
                              hipStream_t stream) {
  const float* x    = (const float*)d_in[0];
  const float* Wih0 = (const float*)d_in[1];
  const float* Whh0 = (const float*)d_in[2];
  const float* b0   = (const float*)d_in[3];
  const float* Wih1 = (const float*)d_in[4];
  const float* Whh1 = (const float*)d_in[5];
  const float* b1   = (const float*)d_in[6];
  float* out = (float*)d_out;

  const size_t NW = 4096ull * 1024;  // weight elems
  const size_t NX = 8192ull * 1024;  // x elems (B*T x H)

  char* ws = (char*)d_ws;
  size_t off = 0;
  auto alloc = [&](size_t bytes) {
    char* p = ws + off;
    off += (bytes + 255) & ~(size_t)255;
    return p;
  };
  unsigned short* wih0b = (unsigned short*)alloc(NW * 2);
  unsigned short* whh0b = (unsigned short*)alloc(NW * 2);
  unsigned short* wih1b = (unsigned short*)alloc(NW * 2);
  unsigned short* whh1b = (unsigned short*)alloc(NW * 2);
  unsigned short* xb    = (unsigned short*)alloc(NX * 2);
  float* ihbuf          = (float*)alloc(8192ull * 4096 * 4);
  unsigned short* h1x   = (unsigned short*)alloc(4ull * HSLOT * 2);
  unsigned short* h2x   = (unsigned short*)alloc(4ull * HSLOT * 2);
  float* Pring          = (float*)alloc(4ull * PSLOT * 4);
  int* tags             = (int*)alloc(3ull * 64 * TSTRIDE * 4);

  hipMemsetAsync(tags, 0, 3ull * 64 * TSTRIDE * 4, stream);
  hipMemsetAsync(h1x, 0, 4ull * HSLOT * 2, stream);
  hipMemsetAsync(h2x, 0, 4ull * HSLOT * 2, stream);

  f2bf_kernel<<<NW / 1024, 256, 0, stream>>>(Wih0, wih0b, (int)NW);
  f2bf_kernel<<<NW / 1024, 256, 0, stream>>>(Whh0, whh0b, (int)NW);
  f2bf_kernel<<<NW / 1024, 256, 0, stream>>>(Wih1, wih1b, (int)NW);
  f2bf_kernel<<<NW / 1024, 256, 0, stream>>>(Whh1, whh1b, (int)NW);
  f2bf_kernel<<<NX / 1024, 256, 0, stream>>>(x, xb, (int)NX);

  // layer-1 input projection (one big GEMM), then the dataflow pipeline
  gemm_bias<<<dim3(64, 32), 256, 0, stream>>>(xb, wih0b, b0, ihbuf, 8192, 4096, 1024);
  lstm_pipe<<<192, 512, 0, stream>>>(ihbuf, whh0b, wih1b, whh1b, b1,
                                     h1x, h2x, Pring, tags, out);
}

// Round 7
// 1285.493 us; speedup vs baseline: 1.5372x; 1.0364x over previous
//
#include <hip/hip_runtime.h>
#include <cstdint>
#include <cstddef>

typedef short s16x8 __attribute__((ext_vector_type(8)));
typedef float f32x4 __attribute__((ext_vector_type(4)));
typedef unsigned long long u64;

__device__ __forceinline__ f32x4 mfma16(s16x8 a, s16x8 b, f32x4 c) {
  return __builtin_amdgcn_mfma_f32_16x16x32_bf16(a, b, c, 0, 0, 0);
}

__device__ __forceinline__ unsigned short f2bf(float f) {
  unsigned u = __float_as_uint(f);
  u = (u + 0x7FFFu + ((u >> 16) & 1u)) >> 16;
  return (unsigned short)u;
}

// LLC-coherent ops (bypass L1/L2, hit the coherence point directly).
__device__ __forceinline__ u64 ld_llc64(const u64* q) {
  return __hip_atomic_load(q, __ATOMIC_RELAXED, __HIP_MEMORY_SCOPE_AGENT);
}
__device__ __forceinline__ float4 load16f_llc(const float* p) {
  union { u64 u[2]; float4 v; } r;
  const u64* q = (const u64*)p;
  r.u[0] = __hip_atomic_load(q,     __ATOMIC_RELAXED, __HIP_MEMORY_SCOPE_AGENT);
  r.u[1] = __hip_atomic_load(q + 1, __ATOMIC_RELAXED, __HIP_MEMORY_SCOPE_AGENT);
  return r.v;
}
__device__ __forceinline__ void store16f_llc(float* p, float4 v) {
  union { float4 v; u64 u[2]; } r; r.v = v;
  u64* q = (u64*)p;
  __hip_atomic_store(q,     r.u[0], __ATOMIC_RELAXED, __HIP_MEMORY_SCOPE_AGENT);
  __hip_atomic_store(q + 1, r.u[1], __ATOMIC_RELAXED, __HIP_MEMORY_SCOPE_AGENT);
}

// Depth-3 pipelined spin with sleep: ~3 loads in flight -> sampling interval
// ~RT/3; sleep keeps idle-poll pressure off the LLC. Monotonic >= check.
__device__ __forceinline__ void spin_tag(const int* t, int target) {
  if (target <= 0) return;
  int a = __hip_atomic_load(t, __ATOMIC_RELAXED, __HIP_MEMORY_SCOPE_AGENT);
  if (a >= target) return;
  int b = __hip_atomic_load(t, __ATOMIC_RELAXED, __HIP_MEMORY_SCOPE_AGENT);
  int c = __hip_atomic_load(t, __ATOMIC_RELAXED, __HIP_MEMORY_SCOPE_AGENT);
  while (a < target) {
    a = b; b = c;
    __builtin_amdgcn_s_sleep(1);
    c = __hip_atomic_load(t, __ATOMIC_RELAXED, __HIP_MEMORY_SCOPE_AGENT);
  }
}

// async global->LDS, 16B per lane. LDS dest = wave-uniform base + lane*16.
__device__ __forceinline__ void gload_lds16(const unsigned short* g,
                                            unsigned short* l) {
  __builtin_amdgcn_global_load_lds(
      (const __attribute__((address_space(1))) unsigned*)(const void*)g,
      (__attribute__((address_space(3))) unsigned*)(void*)l, 16, 0, 0);
}

// ---------------- fp32 -> bf16 conversion ----------------
__global__ void f2bf_kernel(const float* __restrict__ src,
                            unsigned short* __restrict__ dst, int n) {
  int i = (blockIdx.x * blockDim.x + threadIdx.x) * 4;
  if (i >= n) return;
  float4 v = *(const float4*)(src + i);
  ushort4 o;
  o.x = f2bf(v.x); o.y = f2bf(v.y); o.z = f2bf(v.z); o.w = f2bf(v.w);
  *(ushort4*)(dst + i) = o;
}

// fused 4-array weight conversion (one launch instead of four)
__global__ void f2bf4_kernel(const float* __restrict__ s0,
                             const float* __restrict__ s1,
                             const float* __restrict__ s2,
                             const float* __restrict__ s3,
                             unsigned short* __restrict__ d0,
                             unsigned short* __restrict__ d1,
                             unsigned short* __restrict__ d2,
                             unsigned short* __restrict__ d3, int n) {
  int i = (blockIdx.x * blockDim.x + threadIdx.x) * 4;
  if (i >= n) return;
  const float* src = (blockIdx.y == 0) ? s0 : (blockIdx.y == 1) ? s1
                   : (blockIdx.y == 2) ? s2 : s3;
  unsigned short* dst = (blockIdx.y == 0) ? d0 : (blockIdx.y == 1) ? d1
                      : (blockIdx.y == 2) ? d2 : d3;
  float4 v = *(const float4*)(src + i);
  ushort4 o;
  o.x = f2bf(v.x); o.y = f2bf(v.y); o.z = f2bf(v.z); o.w = f2bf(v.w);
  *(ushort4*)(dst + i) = o;
}

// ---------------- GEMM: C[M,N] = A[M,K] * W[N,K]^T + bias ----------------
// m97-structure staging: global_load_lds width=16 into UNPADDED linear LDS
// (the instruction requires dest = wave-uniform base + lane*16; padding
// breaks it). 128x128 tile, BK=32, 4 waves, 4x4 acc/wave, 2 barriers/K-step.
__global__ __launch_bounds__(256) void gemm_bias(
    const unsigned short* __restrict__ A,
    const unsigned short* __restrict__ W,
    const float* __restrict__ bias,
    float* __restrict__ C,
    int M, int N, int K)
{
  __shared__ unsigned short As[128 * 32];
  __shared__ unsigned short Bs[128 * 32];
  const int bm = blockIdx.x, bn = blockIdx.y;
  const int tid = threadIdx.x;
  const int lane = tid & 63, wave = tid >> 6;
  const int wm = wave & 1, wn = wave >> 1;
  const int lr = lane & 15, quad = lane >> 4;
  f32x4 acc[4][4] = {};
  const size_t abase = (size_t)bm * 128 * K;
  const size_t bbase = (size_t)bn * 128 * K;
  // staging geometry: chunk idx = u*256 + tid; row = idx>>2, c = idx&3.
  // LDS linear byte = idx*16 (lane part = lane*16, wave part uniform).
  const int row0 = tid >> 2, c0 = tid & 3;
  for (int k0 = 0; k0 < K; k0 += 32) {
#pragma unroll
    for (int u = 0; u < 2; u++) {
      const int idx = u * 256 + tid;
      const int row = u * 64 + row0;                 // (idx>>2)
      const size_t goff = (size_t)row * K + k0 + c0 * 8;
      unsigned short* lbase_a = As + (u * 256 + wave * 64) * 8;  // uniform
      unsigned short* lbase_b = Bs + (u * 256 + wave * 64) * 8;
      (void)idx;
      gload_lds16(A + abase + goff, lbase_a);
      gload_lds16(W + bbase + goff, lbase_b);
    }
    asm volatile("s_waitcnt vmcnt(0)" ::: "memory");
    __syncthreads();
    s16x8 af[4], bf[4];
#pragma unroll
    for (int i = 0; i < 4; i++)
      af[i] = *(const s16x8*)(As + (wm * 64 + i * 16 + lr) * 32 + quad * 8);
#pragma unroll
    for (int j = 0; j < 4; j++)
      bf[j] = *(const s16x8*)(Bs + (wn * 64 + j * 16 + lr) * 32 + quad * 8);
#pragma unroll
    for (int i = 0; i < 4; i++)
#pragma unroll
      for (int j = 0; j < 4; j++)
        acc[i][j] = mfma16(af[i], bf[j], acc[i][j]);
    __syncthreads();
  }
#pragma unroll
  for (int i = 0; i < 4; i++)
#pragma unroll
    for (int j = 0; j < 4; j++) {
      int col = bn * 128 + wn * 64 + j * 16 + lr;
      float bv = bias ? bias[col] : 0.0f;
#pragma unroll
      for (int r = 0; r < 4; r++) {
        int row = bm * 128 + wm * 64 + i * 16 + quad * 4 + r;
        C[(size_t)row * N + col] = acc[i][j][r] + bv;
      }
    }
}

// ---------------- dataflow 3-stage pipelined LSTM ----------------
// R13 lstm_pipe == R10 verbatim (best verified: 1067us). The R7-R12 arc
// established: (a) stamped-data publish fails (relaxed-store visibility skew
// ~1 RT -> tag overtakes data -> retry storm, FETCH +132MB, 2x confirmed);
// (b) per-wave fetch_add publish regresses (8 serialized RMWs on a polled
// line); (c) tail micro-structure (syncC vs last-arriver, prefetch placement)
// moves <=4%. The ~4.2us/step period is the serialized agent-RT chain +
// max-of-64 straggler jitter -- structural, not tail-polish.
//   cls0 L1 : h1(s) = gate(ih(s) + Whh0 h1(s-1))   tagL1
//   cls1 L2b: P(s)  = Wih1 h1(s) + b1  -> 4-ring   tagL2b (point-to-point)
//   cls2 L2a: h2(s) = gate(P(s) + Whh1 h2(s-1))    tagL2a; writes out
// Tag = completed steps (tid0 store after block drain). Anti-trample, ring-4:
//   cls0 h1(s) over h1(s-4): peers tagL1>=s (top, collective), cls1 tagL2b>=
//   s-3 (top lanes 8-15, 8/wave, collective; syncA < stores). cls1 P(s) over
//   P(s-4): partner tagL2a>=s-3 (lane 8). cls2 h2(s) over h2(s-4): peers
//   tagL2a>=s (top). All overwrites ordered after every prior consumption.
#define TSTRIDE 32          // ints per tag (128B line)
#define HSLOT  32768        // shorts per h slot: 64 blk * 32 batch * 16 dim
#define PSLOT  (64 * 2048)  // floats per P slot: 64 blk * 32 batch * 64 col

__global__ __launch_bounds__(512, 2) void lstm_pipe(
    const float* __restrict__ ih,             // [(b*T+t)*4096 + g*1024 + d]
    const unsigned short* __restrict__ Whh0,  // [4096,1024] bf16
    const unsigned short* __restrict__ Wih1,  // [4096,1024] bf16
    const unsigned short* __restrict__ Whh1,  // [4096,1024] bf16
    const float* __restrict__ b1,             // [4096] fp32
    unsigned short* __restrict__ h1x,         // [4][64][32][16] bf16 (zeroed)
    unsigned short* __restrict__ h2x,         // [4][64][32][16] bf16 (zeroed)
    float* __restrict__ Pring,                // [4][64][32][64] fp32
    int* __restrict__ tags,                   // [3][64][TSTRIDE] (zeroed)
    float* __restrict__ out)                  // [32][256][1024] fp32
{
  const int T = 256, H = 1024;
  const int cls = blockIdx.x >> 6;
  const int blk = blockIdx.x & 63;
  const int tid = threadIdx.x;
  const int lane = tid & 63, wv = tid >> 6;
  const int lr = lane & 15, quad = lane >> 4;

  __shared__ float red[8][32][68];
  __shared__ float pre[32][68];

  const unsigned short* W = (cls == 0) ? Whh0 : (cls == 1) ? Wih1 : Whh1;
  s16x8 bfrag[4][4];
#pragma unroll
  for (int g = 0; g < 4; g++) {
    const unsigned short* wp =
        W + (size_t)(g * 1024 + blk * 16 + lr) * 1024 + wv * 128 + quad * 8;
#pragma unroll
    for (int kb = 0; kb < 4; kb++) bfrag[g][kb] = *(const s16x8*)(wp + kb * 32);
  }

  int* tagL1  = tags;
  int* tagL2b = tags + 64 * TSTRIDE;
  int* tagL2a = tags + 128 * TSTRIDE;
  int* mytag  = tags + (cls * 64 + blk) * TSTRIDE;

  // ---- per-lane poll assignment: one parallel spin covers everything ----
  const int* pollPtr = nullptr;
  int pollDelta = 0;
  if (cls == 0) {
    if (lane < 8)       { pollPtr = tagL1  + (8 * wv + lane) * TSTRIDE;     pollDelta = 0;  }
    else if (lane < 16) { pollPtr = tagL2b + (8 * wv + lane - 8) * TSTRIDE; pollDelta = -3; }
  } else if (cls == 1) {
    if (lane < 8)       { pollPtr = tagL1  + (8 * wv + lane) * TSTRIDE;     pollDelta = 1;  }
    else if (lane == 8) { pollPtr = tagL2a + blk * TSTRIDE;                 pollDelta = -3; }
  } else {
    if (lane < 8)       { pollPtr = tagL2a + (8 * wv + lane) * TSTRIDE;     pollDelta = 0;  }
    else if (lane == 8) { pollPtr = tagL2b + blk * TSTRIDE;                 pollDelta = 1;  }
  }

  const int batch = tid >> 4, jj = tid & 15;
  float cst = 0.0f;

  const int o = tid * 4;
  const int b2 = o >> 6, col0 = o & 63;
  const int gg_ = col0 >> 4, j0 = col0 & 15;
  const float* ihp0 = ih + (size_t)b2 * T * 4096 + gg_ * 1024 + blk * 16 + j0;

  float4 iv = {0.f, 0.f, 0.f, 0.f};
  if (cls == 0)      iv = *(const float4*)(ihp0);
  else if (cls == 1) iv = *(const float4*)(b1 + gg_ * 1024 + blk * 16 + j0);

  for (int s = 0; s < T; s++) {
    // ---- single parallel poll: data tags + anti-trample guards ----
    if (pollPtr) spin_tag(pollPtr, s + pollDelta);
    asm volatile("" ::: "memory");  // no hoisting data loads above polls

    // cls2: issue partner-P load NOW so its RT hides under MFMA
    float4 smp = {0.f, 0.f, 0.f, 0.f};
    if (cls == 2)
      smp = load16f_llc(Pring + (size_t)(s & 3) * PSLOT + blk * 2048 + b2 * 64 + col0);

    // source: cls0 h1(s-1); cls1 h1(s); cls2 h2(s-1). slot = step & 3.
    const unsigned short* src =
        (cls == 0) ? h1x + ((s + 3) & 3) * HSLOT
      : (cls == 1) ? h1x + (s & 3) * HSLOT
                   : h2x + ((s + 3) & 3) * HSLOT;

    // hoist all fragment loads (one LLC latency for the whole step)
    u64 r0[4][2], r1[4][2];
#pragma unroll
    for (int kb = 0; kb < 4; kb++) {
      const int d = wv * 128 + kb * 32 + quad * 8;       // global k-dim
      const unsigned short* pp = src + (d >> 4) * 512 + (d & 15);
      const u64* q0 = (const u64*)(pp + lr * 16);
      const u64* q1 = (const u64*)(pp + (16 + lr) * 16);
      r0[kb][0] = ld_llc64(q0); r0[kb][1] = ld_llc64(q0 + 1);
      r1[kb][0] = ld_llc64(q1); r1[kb][1] = ld_llc64(q1 + 1);
    }

    f32x4 acc0[4] = {}, acc1[4] = {};
#pragma unroll
    for (int kb = 0; kb < 4; kb++) {
      union { u64 u[2]; s16x8 v; } A0, A1;
      A0.u[0] = r0[kb][0]; A0.u[1] = r0[kb][1];
      A1.u[0] = r1[kb][0]; A1.u[1] = r1[kb][1];
#pragma unroll
      for (int g = 0; g < 4; g++) {
        acc0[g] = mfma16(A0.v, bfrag[g][kb], acc0[g]);
        acc1[g] = mfma16(A1.v, bfrag[g][kb], acc1[g]);
      }
    }
#pragma unroll
    for (int g = 0; g < 4; g++)
#pragma unroll
      for (int r = 0; r < 4; r++) {
        red[wv][quad * 4 + r][g * 16 + lr] = acc0[g][r];
        red[wv][16 + quad * 4 + r][g * 16 + lr] = acc1[g][r];
      }
    __syncthreads();  // A (orders: guards < h-stores; red writes < reads)

    // ---- reduce 8 partials + iv (cls2: iv = partner's P(s), prefetched) ----
    float4 sm = (cls == 2) ? smp : iv;
#pragma unroll
    for (int p = 0; p < 8; p++) {
      float4 r = *(const float4*)&red[p][b2][col0];
      sm.x += r.x; sm.y += r.y; sm.z += r.z; sm.w += r.w;
    }

    if (cls == 0 && s + 1 < T)
      iv = *(const float4*)(ihp0 + (size_t)(s + 1) * 4096);

    float hv = 0.0f;
    if (cls == 1) {
      // P(s) = pre-activations, straight to the ring (no gates)
      store16f_llc(Pring + (size_t)(s & 3) * PSLOT + blk * 2048 + b2 * 64 + col0, sm);
    } else {
      // gate exchange is WAVE-INTERNAL: writer lanes of row b2 == reader
      // lanes of batch==b2 (same 16 threads); lgkmcnt orders it.
      *(float4*)&pre[b2][col0] = sm;
      float pi = pre[batch][jj];
      float pf = pre[batch][16 + jj];
      float pg = pre[batch][32 + jj];
      float po = pre[batch][48 + jj];
      float ig = 1.0f / (1.0f + __expf(-pi));
      float fg = 1.0f / (1.0f + __expf(-pf));
      float g  = 1.0f - 2.0f / (__expf(2.0f * pg) + 1.0f);  // tanh, safe
      float og = 1.0f / (1.0f + __expf(-po));
      cst = fg * cst + ig * g;
      hv = og * (1.0f - 2.0f / (__expf(2.0f * cst) + 1.0f));
      unsigned hb32 = f2bf(hv);
      unsigned other = __shfl_xor(hb32, 1);  // partner (same batch, jj^1)
      unsigned* dst = (unsigned*)((cls == 0 ? h1x : h2x) + (s & 3) * HSLOT);
      if ((tid & 1) == 0)
        __hip_atomic_store(dst + blk * 256 + batch * 8 + (jj >> 1),
                           (hb32 & 0xFFFFu) | (other << 16),
                           __ATOMIC_RELAXED, __HIP_MEMORY_SCOPE_AGENT);
    }
    // drain all waves' stores, rendezvous, single publish (R6 discipline)
    asm volatile("s_waitcnt vmcnt(0)" ::: "memory");
    __syncthreads();  // C (also separates red reads from next red writes)
    if (tid == 0)
      __hip_atomic_store(mytag, s + 1, __ATOMIC_RELAXED, __HIP_MEMORY_SCOPE_AGENT);
    if (cls == 2)  // out store after publish: not on the forward path
      out[((size_t)(batch * T + s)) * H + blk * 16 + jj] = hv;
  }
}

// ---------------- launcher ----------------
extern "C" void kernel_launch(void* const* d_in, const int* in_sizes, int n_in,
                              void* d_out, int out_size, void* d_ws, size_t ws_size,
                              hipStream_t stream) {
  const float* x    = (const float*)d_in[0];
  const float* Wih0 = (const float*)d_in[1];
  const float* Whh0 = (const float*)d_in[2];
  const float* b0   = (const float*)d_in[3];
  const float* Wih1 = (const float*)d_in[4];
  const float* Whh1 = (const float*)d_in[5];
  const float* b1   = (const float*)d_in[6];
  float* out = (float*)d_out;

  const size_t NW = 4096ull * 1024;  // weight elems
  const size_t NX = 8192ull * 1024;  // x elems (B*T x H)

  char* ws = (char*)d_ws;
  size_t off = 0;
  auto alloc = [&](size_t bytes) {
    char* p = ws + off;
    off += (bytes + 255) & ~(size_t)255;
    return p;
  };
  unsigned short* wih0b = (unsigned short*)alloc(NW * 2);
  unsigned short* whh0b = (unsigned short*)alloc(NW * 2);
  unsigned short* wih1b = (unsigned short*)alloc(NW * 2);
  unsigned short* whh1b = (unsigned short*)alloc(NW * 2);
  unsigned short* xb    = (unsigned short*)alloc(NX * 2);
  float* ihbuf          = (float*)alloc(8192ull * 4096 * 4);
  unsigned short* h1x   = (unsigned short*)alloc(4ull * HSLOT * 2);
  unsigned short* h2x   = (unsigned short*)alloc(4ull * HSLOT * 2);
  float* Pring          = (float*)alloc(4ull * PSLOT * 4);
  int* tags             = (int*)alloc(3ull * 64 * TSTRIDE * 4);

  hipMemsetAsync(tags, 0, 3ull * 64 * TSTRIDE * 4, stream);
  hipMemsetAsync(h1x, 0, 4ull * HSLOT * 2, stream);
  hipMemsetAsync(h2x, 0, 4ull * HSLOT * 2, stream);

  // weights in one fused launch; x separately
  f2bf4_kernel<<<dim3(NW / 1024, 4), 256, 0, stream>>>(
      Wih0, Whh0, Wih1, Whh1, wih0b, whh0b, wih1b, whh1b, (int)NW);
  f2bf_kernel<<<NX / 1024, 256, 0, stream>>>(x, xb, (int)NX);

  // layer-1 input projection (one big GEMM), then the dataflow pipeline
  gemm_bias<<<dim3(64, 32), 256, 0, stream>>>(xb, wih0b, b0, ihbuf, 8192, 4096, 1024);
  lstm_pipe<<<192, 512, 0, stream>>>(ihbuf, whh0b, wih1b, whh1b, b1,
                                     h1x, h2x, Pring, tags, out);
}

// Round 8
// 1240.218 us; speedup vs baseline: 1.5933x; 1.0365x over previous
//
#include <hip/hip_runtime.h>
#include <cstdint>
#include <cstddef>

typedef short s16x8 __attribute__((ext_vector_type(8)));
typedef float f32x4 __attribute__((ext_vector_type(4)));
typedef unsigned long long u64;

__device__ __forceinline__ f32x4 mfma16(s16x8 a, s16x8 b, f32x4 c) {
  return __builtin_amdgcn_mfma_f32_16x16x32_bf16(a, b, c, 0, 0, 0);
}

__device__ __forceinline__ unsigned short f2bf(float f) {
  unsigned u = __float_as_uint(f);
  u = (u + 0x7FFFu + ((u >> 16) & 1u)) >> 16;
  return (unsigned short)u;
}

// LLC-coherent ops (bypass L1/L2, hit the coherence point directly).
__device__ __forceinline__ u64 ld_llc64(const u64* q) {
  return __hip_atomic_load(q, __ATOMIC_RELAXED, __HIP_MEMORY_SCOPE_AGENT);
}
__device__ __forceinline__ float4 load16f_llc(const float* p) {
  union { u64 u[2]; float4 v; } r;
  const u64* q = (const u64*)p;
  r.u[0] = __hip_atomic_load(q,     __ATOMIC_RELAXED, __HIP_MEMORY_SCOPE_AGENT);
  r.u[1] = __hip_atomic_load(q + 1, __ATOMIC_RELAXED, __HIP_MEMORY_SCOPE_AGENT);
  return r.v;
}
__device__ __forceinline__ void store16f_llc(float* p, float4 v) {
  union { float4 v; u64 u[2]; } r; r.v = v;
  u64* q = (u64*)p;
  __hip_atomic_store(q,     r.u[0], __ATOMIC_RELAXED, __HIP_MEMORY_SCOPE_AGENT);
  __hip_atomic_store(q + 1, r.u[1], __ATOMIC_RELAXED, __HIP_MEMORY_SCOPE_AGENT);
}

// Depth-3 pipelined spin with sleep: ~3 loads in flight -> sampling interval
// ~RT/3; sleep keeps idle-poll pressure off the LLC. Monotonic >= check.
__device__ __forceinline__ void spin_tag(const int* t, int target) {
  if (target <= 0) return;
  int a = __hip_atomic_load(t, __ATOMIC_RELAXED, __HIP_MEMORY_SCOPE_AGENT);
  if (a >= target) return;
  int b = __hip_atomic_load(t, __ATOMIC_RELAXED, __HIP_MEMORY_SCOPE_AGENT);
  int c = __hip_atomic_load(t, __ATOMIC_RELAXED, __HIP_MEMORY_SCOPE_AGENT);
  while (a < target) {
    a = b; b = c;
    __builtin_amdgcn_s_sleep(1);
    c = __hip_atomic_load(t, __ATOMIC_RELAXED, __HIP_MEMORY_SCOPE_AGENT);
  }
}

// ---------------- fp32 -> bf16 conversion ----------------
__global__ void f2bf_kernel(const float* __restrict__ src,
                            unsigned short* __restrict__ dst, int n) {
  int i = (blockIdx.x * blockDim.x + threadIdx.x) * 4;
  if (i >= n) return;
  float4 v = *(const float4*)(src + i);
  ushort4 o;
  o.x = f2bf(v.x); o.y = f2bf(v.y); o.z = f2bf(v.z); o.w = f2bf(v.w);
  *(ushort4*)(dst + i) = o;
}

// fused 4-array weight conversion (one launch instead of four)
__global__ void f2bf4_kernel(const float* __restrict__ s0,
                             const float* __restrict__ s1,
                             const float* __restrict__ s2,
                             const float* __restrict__ s3,
                             unsigned short* __restrict__ d0,
                             unsigned short* __restrict__ d1,
                             unsigned short* __restrict__ d2,
                             unsigned short* __restrict__ d3, int n) {
  int i = (blockIdx.x * blockDim.x + threadIdx.x) * 4;
  if (i >= n) return;
  const float* src = (blockIdx.y == 0) ? s0 : (blockIdx.y == 1) ? s1
                   : (blockIdx.y == 2) ? s2 : s3;
  unsigned short* dst = (blockIdx.y == 0) ? d0 : (blockIdx.y == 1) ? d1
                      : (blockIdx.y == 2) ? d2 : d3;
  float4 v = *(const float4*)(src + i);
  ushort4 o;
  o.x = f2bf(v.x); o.y = f2bf(v.y); o.z = f2bf(v.z); o.w = f2bf(v.w);
  *(ushort4*)(dst + i) = o;
}

// ---------------- fused: ih-GEMM producers + 3-stage pipelined LSTM ----------
// R14: the 180us ih-projection GEMM moves INTO the pipeline kernel as 64
// producer blocks (bid 0-63) running on the CUs the 192-block pipeline never
// used. ih re-laid-out as [t][b][4096] so one 128-row M-tile = 4 timesteps.
// Worker w computes tiles tau = w + 64k (k=0..31): chunk c (= 4 steps) is
// complete when its 32 N-tiles are done -> fetch_add(chunkcnt[c]); cls0
// polls chunkcnt[s>>2] and [(s+1)>>2] >= 32 (lanes 16/17 of its parallel
// poll) and reads ih via LLC loads (same-kernel producer: plain loads could
// hit a stale/non-coherent XCD L2 -> agent scope mandatory).
// Production outpaces consumption (~12us/chunk vs 16.7us/chunk consumed), so
// after a ~2-chunk startup stall the GEMM is fully hidden under the pipeline.
// Workers depend on nothing -> no deadlock. 256 blocks at 99KB LDS = 1/CU,
// all co-resident. lstm protocol = R10/R13 verbatim (best verified 1067us).
//   cls0 L1 : h1(s) = gate(ih(s) + Whh0 h1(s-1))   tagL1
//   cls1 L2b: P(s)  = Wih1 h1(s) + b1  -> 4-ring   tagL2b (point-to-point)
//   cls2 L2a: h2(s) = gate(P(s) + Whh1 h2(s-1))    tagL2a; writes out
// Anti-trample (ring-4, lagging): cls0 h1(s) over h1(s-4): peers tagL1>=s,
// cls1 tagL2b>=s-3. cls1 P(s) over P(s-4): partner tagL2a>=s-3. cls2 h2(s)
// over h2(s-4): peers tagL2a>=s. All ordered before overwrite via syncA/C.
#define TSTRIDE 32          // ints per tag (128B line)
#define HSLOT  32768        // shorts per h slot: 64 blk * 32 batch * 16 dim
#define PSLOT  (64 * 2048)  // floats per P slot: 64 blk * 32 batch * 64 col
#define CSTRIDE 32          // ints per chunk counter (128B line)

__global__ __launch_bounds__(512, 2) void lstm_fused(
    float* __restrict__ ih,                   // [256 t][32 b][4096] fp32
    const unsigned short* __restrict__ Whh0,  // [4096,1024] bf16
    const unsigned short* __restrict__ Wih1,  // [4096,1024] bf16
    const unsigned short* __restrict__ Whh1,  // [4096,1024] bf16
    const float* __restrict__ b1,             // [4096] fp32
    unsigned short* __restrict__ h1x,         // [4][64][32][16] bf16 (zeroed)
    unsigned short* __restrict__ h2x,         // [4][64][32][16] bf16 (zeroed)
    float* __restrict__ Pring,                // [4][64][32][64] fp32
    int* __restrict__ tags,                   // [3][64][TSTRIDE] (zeroed)
    float* __restrict__ out,                  // [32][256][1024] fp32
    const unsigned short* __restrict__ xb,    // [32 b][256 t][1024] bf16
    const unsigned short* __restrict__ Wih0,  // [4096,1024] bf16
    const float* __restrict__ b0,             // [4096] fp32
    int* __restrict__ chunkcnt)               // [64][CSTRIDE] (zeroed)
{
  const int T = 256, H = 1024;
  const int tid = threadIdx.x;
  const int lane = tid & 63, wv = tid >> 6;
  const int lr = lane & 15, quad = lane >> 4;

  __shared__ float red[8][32][68];
  __shared__ float pre[32][68];
  __shared__ unsigned short As[128 * 40];
  __shared__ unsigned short Bs[128 * 40];

  if (blockIdx.x < 64) {
    // ================= ih-GEMM producer =================
    const int w = blockIdx.x;
    const int wm = wv & 1, wn = wv >> 1;          // 2 x 4 wave grid
    const int row = tid >> 2, seg = tid & 3;      // staging: 1 uint4/thread
    for (int it = 0; it < 32; ++it) {
      const int tau = w + it * 64;
      const int tc = tau >> 5, nc = tau & 31;
      f32x4 acc[4][2] = {};
      // A row (t*32+b order): m = tc*128+row -> t = tc*4+(row>>5), b = row&31
      const unsigned short* pa =
          xb + ((size_t)((row & 31) * 256 + tc * 4 + (row >> 5))) * 1024 + seg * 8;
      const unsigned short* pb =
          Wih0 + ((size_t)(nc * 128 + row)) * 1024 + seg * 8;
      uint4 ra = *(const uint4*)(pa);
      uint4 rb = *(const uint4*)(pb);
      for (int k0 = 0; k0 < 1024; k0 += 32) {
        *(uint4*)(As + row * 40 + seg * 8) = ra;
        *(uint4*)(Bs + row * 40 + seg * 8) = rb;
        __syncthreads();
        if (k0 + 32 < 1024) {              // prefetch next K-slab under MFMA
          ra = *(const uint4*)(pa + k0 + 32);
          rb = *(const uint4*)(pb + k0 + 32);
        }
        s16x8 af[4], bfr[2];
#pragma unroll
        for (int i = 0; i < 4; i++)
          af[i] = *(const s16x8*)(As + (wm * 64 + i * 16 + lr) * 40 + quad * 8);
#pragma unroll
        for (int j = 0; j < 2; j++)
          bfr[j] = *(const s16x8*)(Bs + (wn * 32 + j * 16 + lr) * 40 + quad * 8);
#pragma unroll
        for (int i = 0; i < 4; i++)
#pragma unroll
          for (int j = 0; j < 2; j++)
            acc[i][j] = mfma16(af[i], bfr[j], acc[i][j]);
        __syncthreads();
      }
      // epilogue: LLC stores (same-kernel consumer), drain, count chunk
#pragma unroll
      for (int i = 0; i < 4; i++)
#pragma unroll
        for (int j = 0; j < 2; j++) {
          const int col = nc * 128 + wn * 32 + j * 16 + lr;
          const float bv = b0[col];
#pragma unroll
          for (int r = 0; r < 4; r++) {
            const int rowm = tc * 128 + wm * 64 + i * 16 + quad * 4 + r;
            __hip_atomic_store(ih + (size_t)rowm * 4096 + col,
                               acc[i][j][r] + bv,
                               __ATOMIC_RELAXED, __HIP_MEMORY_SCOPE_AGENT);
          }
        }
      asm volatile("s_waitcnt vmcnt(0)" ::: "memory");
      __syncthreads();
      if (tid == 0)
        __hip_atomic_fetch_add(chunkcnt + (tc << 5), 1,
                               __ATOMIC_RELAXED, __HIP_MEMORY_SCOPE_AGENT);
    }
    return;
  }

  // ================= 3-stage LSTM pipeline (R10 verbatim + ih remap) =======
  const int p = blockIdx.x - 64;
  const int cls = p >> 6;
  const int blk = p & 63;

  const unsigned short* W = (cls == 0) ? Whh0 : (cls == 1) ? Wih1 : Whh1;
  s16x8 bfrag[4][4];
#pragma unroll
  for (int g = 0; g < 4; g++) {
    const unsigned short* wp =
        W + (size_t)(g * 1024 + blk * 16 + lr) * 1024 + wv * 128 + quad * 8;
#pragma unroll
    for (int kb = 0; kb < 4; kb++) bfrag[g][kb] = *(const s16x8*)(wp + kb * 32);
  }

  int* tagL1  = tags;
  int* tagL2b = tags + 64 * TSTRIDE;
  int* tagL2a = tags + 128 * TSTRIDE;
  int* mytag  = tags + (cls * 64 + blk) * TSTRIDE;

  // ---- per-lane poll assignment: one parallel spin covers everything ----
  const int* pollPtr = nullptr;
  int pollDelta = 0;
  if (cls == 0) {
    if (lane < 8)       { pollPtr = tagL1  + (8 * wv + lane) * TSTRIDE;     pollDelta = 0;  }
    else if (lane < 16) { pollPtr = tagL2b + (8 * wv + lane - 8) * TSTRIDE; pollDelta = -3; }
  } else if (cls == 1) {
    if (lane < 8)       { pollPtr = tagL1  + (8 * wv + lane) * TSTRIDE;     pollDelta = 1;  }
    else if (lane == 8) { pollPtr = tagL2a + blk * TSTRIDE;                 pollDelta = -3; }
  } else {
    if (lane < 8)       { pollPtr = tagL2a + (8 * wv + lane) * TSTRIDE;     pollDelta = 0;  }
    else if (lane == 8) { pollPtr = tagL2b + blk * TSTRIDE;                 pollDelta = 1;  }
  }

  const int batch = tid >> 4, jj = tid & 15;
  float cst = 0.0f;

  const int o = tid * 4;
  const int b2 = o >> 6, col0 = o & 63;
  const int gg_ = col0 >> 4, j0 = col0 & 15;
  const int coloff = gg_ * 1024 + blk * 16 + j0;   // column offset in [4096]

  float4 iv = {0.f, 0.f, 0.f, 0.f};
  if (cls == 1) iv = *(const float4*)(b1 + coloff);

  for (int s = 0; s < T; s++) {
    // ---- single parallel poll: data tags + anti-trample guards ----
    if (pollPtr) spin_tag(pollPtr, s + pollDelta);
    if (cls == 0) {  // ih chunk readiness (producers are in this kernel)
      int c1 = (s + 1) >> 2; if (c1 > 63) c1 = 63;
      if (lane == 16)      spin_tag(chunkcnt + (c1 << 5), 32);
      else if (lane == 17) spin_tag(chunkcnt + ((s >> 2) << 5), 32);
    }
    asm volatile("" ::: "memory");  // no hoisting data loads above polls

    // cls0 first step: ih(0) load (chunk 0 just polled); RT hides under MFMA
    if (cls == 0 && s == 0)
      iv = load16f_llc(ih + (size_t)b2 * 4096 + coloff);

    // cls2: issue partner-P load NOW so its RT hides under MFMA
    float4 smp = {0.f, 0.f, 0.f, 0.f};
    if (cls == 2)
      smp = load16f_llc(Pring + (size_t)(s & 3) * PSLOT + blk * 2048 + b2 * 64 + col0);

    // source: cls0 h1(s-1); cls1 h1(s); cls2 h2(s-1). slot = step & 3.
    const unsigned short* src =
        (cls == 0) ? h1x + ((s + 3) & 3) * HSLOT
      : (cls == 1) ? h1x + (s & 3) * HSLOT
                   : h2x + ((s + 3) & 3) * HSLOT;

    // hoist all fragment loads (one LLC latency for the whole step)
    u64 r0[4][2], r1[4][2];
#pragma unroll
    for (int kb = 0; kb < 4; kb++) {
      const int d = wv * 128 + kb * 32 + quad * 8;       // global k-dim
      const unsigned short* pp = src + (d >> 4) * 512 + (d & 15);
      const u64* q0 = (const u64*)(pp + lr * 16);
      const u64* q1 = (const u64*)(pp + (16 + lr) * 16);
      r0[kb][0] = ld_llc64(q0); r0[kb][1] = ld_llc64(q0 + 1);
      r1[kb][0] = ld_llc64(q1); r1[kb][1] = ld_llc64(q1 + 1);
    }

    f32x4 acc0[4] = {}, acc1[4] = {};
#pragma unroll
    for (int kb = 0; kb < 4; kb++) {
      union { u64 u[2]; s16x8 v; } A0, A1;
      A0.u[0] = r0[kb][0]; A0.u[1] = r0[kb][1];
      A1.u[0] = r1[kb][0]; A1.u[1] = r1[kb][1];
#pragma unroll
      for (int g = 0; g < 4; g++) {
        acc0[g] = mfma16(A0.v, bfrag[g][kb], acc0[g]);
        acc1[g] = mfma16(A1.v, bfrag[g][kb], acc1[g]);
      }
    }
#pragma unroll
    for (int g = 0; g < 4; g++)
#pragma unroll
      for (int r = 0; r < 4; r++) {
        red[wv][quad * 4 + r][g * 16 + lr] = acc0[g][r];
        red[wv][16 + quad * 4 + r][g * 16 + lr] = acc1[g][r];
      }
    __syncthreads();  // A (orders: guards < h-stores; red writes < reads)

    // ---- reduce 8 partials + iv (cls2: iv = partner's P(s), prefetched) ----
    float4 sm = (cls == 2) ? smp : iv;
#pragma unroll
    for (int p2 = 0; p2 < 8; p2++) {
      float4 r = *(const float4*)&red[p2][b2][col0];
      sm.x += r.x; sm.y += r.y; sm.z += r.z; sm.w += r.w;
    }

    if (cls == 0 && s + 1 < T)   // prefetch ih(s+1); chunk polled at top
      iv = load16f_llc(ih + ((size_t)(s + 1) * 32 + b2) * 4096 + coloff);

    float hv = 0.0f;
    if (cls == 1) {
      // P(s) = pre-activations, straight to the ring (no gates)
      store16f_llc(Pring + (size_t)(s & 3) * PSLOT + blk * 2048 + b2 * 64 + col0, sm);
    } else {
      // gate exchange is WAVE-INTERNAL: writer lanes of row b2 == reader
      // lanes of batch==b2 (same 16 threads); lgkmcnt orders it.
      *(float4*)&pre[b2][col0] = sm;
      float pi = pre[batch][jj];
      float pf = pre[batch][16 + jj];
      float pg = pre[batch][32 + jj];
      float po = pre[batch][48 + jj];
      float ig = 1.0f / (1.0f + __expf(-pi));
      float fg = 1.0f / (1.0f + __expf(-pf));
      float g  = 1.0f - 2.0f / (__expf(2.0f * pg) + 1.0f);  // tanh, safe
      float og = 1.0f / (1.0f + __expf(-po));
      cst = fg * cst + ig * g;
      hv = og * (1.0f - 2.0f / (__expf(2.0f * cst) + 1.0f));
      unsigned hb32 = f2bf(hv);
      unsigned other = __shfl_xor(hb32, 1);  // partner (same batch, jj^1)
      unsigned* dst = (unsigned*)((cls == 0 ? h1x : h2x) + (s & 3) * HSLOT);
      if ((tid & 1) == 0)
        __hip_atomic_store(dst + blk * 256 + batch * 8 + (jj >> 1),
                           (hb32 & 0xFFFFu) | (other << 16),
                           __ATOMIC_RELAXED, __HIP_MEMORY_SCOPE_AGENT);
    }
    // drain all waves' stores, rendezvous, single publish (R6 discipline)
    asm volatile("s_waitcnt vmcnt(0)" ::: "memory");
    __syncthreads();  // C (also separates red reads from next red writes)
    if (tid == 0)
      __hip_atomic_store(mytag, s + 1, __ATOMIC_RELAXED, __HIP_MEMORY_SCOPE_AGENT);
    if (cls == 2)  // out store after publish: not on the forward path
      out[((size_t)(batch * T + s)) * H + blk * 16 + jj] = hv;
  }
}

// ---------------- launcher ----------------
extern "C" void kernel_launch(void* const* d_in, const int* in_sizes, int n_in,
                              void* d_out, int out_size, void* d_ws, size_t ws_size,
                              hipStream_t stream) {
  const float* x    = (const float*)d_in[0];
  const float* Wih0 = (const float*)d_in[1];
  const float* Whh0 = (const float*)d_in[2];
  const float* b0   = (const float*)d_in[3];
  const float* Wih1 = (const float*)d_in[4];
  const float* Whh1 = (const float*)d_in[5];
  const float* b1   = (const float*)d_in[6];
  float* out = (float*)d_out;

  const size_t NW = 4096ull * 1024;  // weight elems
  const size_t NX = 8192ull * 1024;  // x elems (B*T x H)

  char* ws = (char*)d_ws;
  size_t off = 0;
  auto alloc = [&](size_t bytes) {
    char* p = ws + off;
    off += (bytes + 255) & ~(size_t)255;
    return p;
  };
  unsigned short* wih0b = (unsigned short*)alloc(NW * 2);
  unsigned short* whh0b = (unsigned short*)alloc(NW * 2);
  unsigned short* wih1b = (unsigned short*)alloc(NW * 2);
  unsigned short* whh1b = (unsigned short*)alloc(NW * 2);
  unsigned short* xb    = (unsigned short*)alloc(NX * 2);
  float* ihbuf          = (float*)alloc(8192ull * 4096 * 4);
  unsigned short* h1x   = (unsigned short*)alloc(4ull * HSLOT * 2);
  unsigned short* h2x   = (unsigned short*)alloc(4ull * HSLOT * 2);
  float* Pring          = (float*)alloc(4ull * PSLOT * 4);
  int* tags             = (int*)alloc(3ull * 64 * TSTRIDE * 4);
  int* chunkcnt         = (int*)alloc(64ull * CSTRIDE * 4);

  hipMemsetAsync(tags, 0, 3ull * 64 * TSTRIDE * 4, stream);
  hipMemsetAsync(h1x, 0, 4ull * HSLOT * 2, stream);
  hipMemsetAsync(h2x, 0, 4ull * HSLOT * 2, stream);
  hipMemsetAsync(chunkcnt, 0, 64ull * CSTRIDE * 4, stream);

  // weights in one fused launch; x separately
  f2bf4_kernel<<<dim3(NW / 1024, 4), 256, 0, stream>>>(
      Wih0, Whh0, Wih1, Whh1, wih0b, whh0b, wih1b, whh1b, (int)NW);
  f2bf_kernel<<<NX / 1024, 256, 0, stream>>>(x, xb, (int)NX);

  // one fused kernel: 64 ih-GEMM producer blocks + 192 pipeline blocks
  lstm_fused<<<256, 512, 0, stream>>>(ihbuf, whh0b, wih1b, whh1b, b1,
                                      h1x, h2x, Pring, tags, out,
                                      xb, wih0b, b0, chunkcnt);
}